// Round 6
// baseline (630.172 us; speedup 1.0000x reference)
//
#include <hip/hip_runtime.h>
#include <math.h>

#define D_IN 512
#define F1   16
#define F2   7

#define BKT_SHIFT 8                 // 256 nodes per bucket
#define PK_SHIFT  18                // packed word: src | (dst&255)<<18  (needs n <= 2^18)
#define PK_MASK   ((1u << PK_SHIFT) - 1u)
#define A_CHUNK   8192              // edges per workgroup in binning passes
#define B_CAP     16384             // LDS staging capacity in CSR pass

// ---- pass A1: per-bucket edge histogram (LDS-aggregated) ----
__global__ __launch_bounds__(256) void binhist_kernel(const int* __restrict__ dst,
                                                      int* __restrict__ bucket_cnt,
                                                      int E, int NB) {
    __shared__ int lh[512];
    for (int i = threadIdx.x; i < 512; i += 256) lh[i] = 0;
    __syncthreads();
    int base = blockIdx.x * A_CHUNK;
#pragma unroll
    for (int i = 0; i < A_CHUNK / 256; ++i) {
        int t = base + i * 256 + threadIdx.x;
        if (t < E) {
            int d = __builtin_nontemporal_load(&dst[t]);
            atomicAdd(&lh[d >> BKT_SHIFT], 1);
        }
    }
    __syncthreads();
    for (int i = threadIdx.x; i < NB; i += 256) {
        int v = lh[i];
        if (v) atomicAdd(&bucket_cnt[i], v);
    }
}

// ---- bucket scan ----
__global__ __launch_bounds__(512) void bucketscan_kernel(const int* __restrict__ bucket_cnt,
                                                         int* __restrict__ bucket_base,
                                                         int* __restrict__ bucket_cursor,
                                                         int NB, int E) {
    __shared__ int sm[512];
    int tid = threadIdx.x;
    int v = (tid < NB) ? bucket_cnt[tid] : 0;
    sm[tid] = v;
    __syncthreads();
    for (int off = 1; off < 512; off <<= 1) {
        int t = (tid >= off) ? sm[tid - off] : 0;
        __syncthreads();
        sm[tid] += t;
        __syncthreads();
    }
    if (tid < NB) {
        int ex = sm[tid] - v;
        bucket_base[tid] = ex;
        bucket_cursor[tid] = ex;
    }
    if (tid == 0) bucket_base[NB] = E;
}

// ---- pass A2: bin edges into bucket regions with segment-contiguous writes ----
__global__ __launch_bounds__(256) void bin_kernel(const int* __restrict__ src,
                                                  const int* __restrict__ dst,
                                                  int* __restrict__ bucket_cursor,
                                                  unsigned int* __restrict__ binned,
                                                  int E, int NB) {
    __shared__ int lh[512];
    __shared__ int lbase[512];
    __shared__ int lcur[512];
    __shared__ int sdelta[512];
    __shared__ int sA[512], sB[512];
    __shared__ unsigned int rbuf[A_CHUNK];
    __shared__ int rdelta[A_CHUNK];
    int tid = threadIdx.x;
    for (int i = tid; i < 512; i += 256) lh[i] = 0;
    __syncthreads();

    int base = blockIdx.x * A_CHUNK;
    int dcache[A_CHUNK / 256];
    int scache[A_CHUNK / 256];
#pragma unroll
    for (int i = 0; i < A_CHUNK / 256; ++i) {
        int t = base + i * 256 + tid;
        int d = -1, s = 0;
        if (t < E) {
            d = __builtin_nontemporal_load(&dst[t]);
            s = __builtin_nontemporal_load(&src[t]);
            atomicAdd(&lh[d >> BKT_SHIFT], 1);
        }
        dcache[i] = d;
        scache[i] = s;
    }
    __syncthreads();

    for (int i = tid; i < 512; i += 256) sA[i] = lh[i];
    __syncthreads();
    int* psrc = sA; int* pdst = sB;
    for (int off = 1; off < 512; off <<= 1) {
        for (int i = tid; i < 512; i += 256)
            pdst[i] = psrc[i] + ((i >= off) ? psrc[i - off] : 0);
        __syncthreads();
        int* tmp = psrc; psrc = pdst; pdst = tmp;
    }
    for (int i = tid; i < 512; i += 256) {
        int ex = psrc[i] - lh[i];
        lbase[i] = ex;
        lcur[i] = ex;
    }
    __syncthreads();

    for (int b = tid; b < NB; b += 256) {
        int c = lh[b];
        int g = c ? atomicAdd(&bucket_cursor[b], c) : 0;
        sdelta[b] = g - lbase[b];
    }
    __syncthreads();

#pragma unroll
    for (int i = 0; i < A_CHUNK / 256; ++i) {
        int d = dcache[i];
        if (d >= 0) {
            int b = d >> BKT_SHIFT;
            int p = atomicAdd(&lcur[b], 1);
            rbuf[p] = (unsigned int)scache[i] | ((unsigned int)(d & 255) << PK_SHIFT);
            rdelta[p] = sdelta[b];
        }
    }
    __syncthreads();

    int total = min(A_CHUNK, E - base);
    for (int p = tid; p < total; p += 256)
        binned[rdelta[p] + p] = rbuf[p];
}

// ---- pass B: per-bucket local counting sort -> adj, row_ptr/row_end/dinv ----
__global__ __launch_bounds__(256) void csr_kernel(const unsigned int* __restrict__ binned,
                                                  const int* __restrict__ bucket_base,
                                                  int* __restrict__ row_ptr,
                                                  int* __restrict__ row_end,
                                                  float* __restrict__ dinv,
                                                  int* __restrict__ adj, int n) {
    __shared__ int lh[256], lscan[256], lcur[256];
    __shared__ unsigned int rbuf[B_CAP];
    int b = blockIdx.x;
    int tid = threadIdx.x;
    int gbase = bucket_base[b];
    int gend  = bucket_base[b + 1];
    int m = gend - gbase;
    lh[tid] = 0;
    __syncthreads();
    for (int i = tid; i < m; i += 256) {
        unsigned int w = __builtin_nontemporal_load(&binned[gbase + i]);
        if (i < B_CAP) rbuf[i] = w;
        atomicAdd(&lh[w >> PK_SHIFT], 1);
    }
    __syncthreads();
    int v = lh[tid];
    lscan[tid] = v;
    __syncthreads();
    for (int off = 1; off < 256; off <<= 1) {
        int t = (tid >= off) ? lscan[tid - off] : 0;
        __syncthreads();
        lscan[tid] += t;
        __syncthreads();
    }
    int ex = lscan[tid] - v;  // exclusive
    int node = (b << BKT_SHIFT) + tid;
    if (node < n) {
        row_ptr[node] = gbase + ex;
        row_end[node] = gbase + ex + v;
        dinv[node] = rsqrtf((float)v + 1.0f);
    }
    lcur[tid] = ex;
    __syncthreads();
    for (int i = tid; i < m; i += 256) {
        unsigned int w = (i < B_CAP) ? rbuf[i] : binned[gbase + i];
        int d = (int)(w >> PK_SHIFT);
        int s = (int)(w & PK_MASK);
        int p = atomicAdd(&lcur[d], 1);
        adj[gbase + p] = s;
    }
}

// ---- layer-1 matmul: h1s = (x @ W1) * dinv[node], wave-per-node, coalesced ----
// Wave owns a node row: 2x float4/lane = 2048 B contiguous (1 KB per load instr).
// Lane l covers k in {4l..4l+3} and {256+4l..256+4l+3}; W1 slice register-resident
// (8 rows x 16 floats = 128 VGPRs), amortized over ~n/NWAVES nodes via grid-stride.
// Reduction: fold halves values/lane 16->1 selecting j-bit by lane-bit, j=(lane>>2)&15.
__global__ __launch_bounds__(256, 2) void mm1_kernel(const float* __restrict__ x,
                                                     const float* __restrict__ W1,
                                                     const float* __restrict__ dinv,
                                                     float* __restrict__ h1s, int n) {
    int lane = threadIdx.x & 63;
    int wave = (blockIdx.x * 256 + threadIdx.x) >> 6;
    int NW = gridDim.x << 2;   // total waves

    // register-resident W1 slice: wreg[g*4+kl][j4] = W1[g*256 + 4*lane + kl][4*j4..+3]
    float4 wreg[8][4];
#pragma unroll
    for (int g = 0; g < 2; ++g)
#pragma unroll
        for (int kl = 0; kl < 4; ++kl) {
            const float4* wr = (const float4*)(W1 + (size_t)(g * 256 + 4 * lane + kl) * F1);
#pragma unroll
            for (int j4 = 0; j4 < 4; ++j4) wreg[g * 4 + kl][j4] = wr[j4];
        }

    int node = wave;
    if (node >= n) return;
    const float4* xr = (const float4*)(x + (size_t)node * D_IN);
    float4 x0 = xr[lane], x1 = xr[64 + lane];

    while (node < n) {
        int nxt = node + NW;
        float4 c0 = x0, c1 = x1;
        if (nxt < n) {   // prefetch next row while we compute
            const float4* xn = (const float4*)(x + (size_t)nxt * D_IN);
            x0 = xn[lane]; x1 = xn[64 + lane];
        }

        float acc[F1];
#pragma unroll
        for (int j = 0; j < F1; ++j) acc[j] = 0.0f;
#pragma unroll
        for (int g = 0; g < 2; ++g) {
            const float* xv = g == 0 ? (const float*)&c0 : (const float*)&c1;
#pragma unroll
            for (int kl = 0; kl < 4; ++kl) {
                float xe = xv[kl];
                const float* wf = (const float*)&wreg[g * 4 + kl][0];
#pragma unroll
                for (int j = 0; j < F1; ++j) acc[j] += xe * wf[j];
            }
        }

        // fold-reduce: masks 32,16,8,4 pick j-bits 3..0 from lane bits 5..2
        int c = F1;
#pragma unroll
        for (int m = 32; m >= 4; m >>= 1) {
            int c2 = c >> 1;
            bool hi = (lane & m) != 0;
#pragma unroll
            for (int i = 0; i < 8; ++i) {
                if (i >= c2) break;
                float send = hi ? acc[i] : acc[i + c2];
                float keep = hi ? acc[i + c2] : acc[i];
                acc[i] = keep + __shfl_xor(send, m);
            }
            c = c2;
        }
        // butterfly over lane bits 0,1
        acc[0] += __shfl_xor(acc[0], 1);
        acc[0] += __shfl_xor(acc[0], 2);

        float di = dinv[node];   // wave-uniform -> scalar load
        if ((lane & 3) == 0)
            h1s[(size_t)node * F1 + (lane >> 2)] = acc[0] * di;

        node = nxt;
    }
}

// ---- layer-1 gather + fused finalize: acc1 = relu(dinv*(sum + h1s[node]) + b1) ----
__global__ __launch_bounds__(256) void agg1_kernel(const int* __restrict__ row_ptr,
                                                   const int* __restrict__ row_end,
                                                   const int* __restrict__ adj,
                                                   const float* __restrict__ h,
                                                   const float* __restrict__ dinv,
                                                   const float* __restrict__ b1,
                                                   float* __restrict__ acc, int n) {
    int t = blockIdx.x * 256 + threadIdx.x;
    int node = t >> 4, j = t & 15;
    if (node >= n) return;
    int s = row_ptr[node], e = row_end[node];
    float a0 = 0.0f, a1 = 0.0f;
    int k = s;
    for (; k + 1 < e; k += 2) {
        int s0 = adj[k], s1 = adj[k + 1];
        a0 += h[(size_t)s0 * F1 + j];
        a1 += h[(size_t)s1 * F1 + j];
    }
    if (k < e) a0 += h[(size_t)adj[k] * F1 + j];
    float di = dinv[node];
    float v = di * (a0 + a1 + h[(size_t)node * F1 + j]) + b1[j];
    acc[(size_t)node * F1 + j] = v > 0.0f ? v : 0.0f;
}

// ---------------- layer-2 matmul: h2s = (h @ W2) * dinv, padded stride 8 ----------------
__global__ __launch_bounds__(256) void mm2_kernel(const float* __restrict__ hin,
                                                  const float* __restrict__ W2,
                                                  const float* __restrict__ dinv,
                                                  float* __restrict__ h2s, int n) {
    int t = blockIdx.x * blockDim.x + threadIdx.x;
    if (t >= n) return;
    const float4* hr = (const float4*)(hin + (size_t)t * F1);
    float hv[F1];
#pragma unroll
    for (int q = 0; q < 4; ++q) {
        float4 v = hr[q];
        hv[4 * q + 0] = v.x; hv[4 * q + 1] = v.y;
        hv[4 * q + 2] = v.z; hv[4 * q + 3] = v.w;
    }
    float acc[F2];
#pragma unroll
    for (int j = 0; j < F2; ++j) acc[j] = 0.0f;
#pragma unroll
    for (int k = 0; k < F1; ++k) {
        float xv = hv[k];
#pragma unroll
        for (int j = 0; j < F2; ++j) acc[j] += xv * W2[k * F2 + j];
    }
    float di = dinv[t];
    float* outp = h2s + (size_t)t * 8;
#pragma unroll
    for (int j = 0; j < F2; ++j) outp[j] = acc[j] * di;
    outp[7] = 0.0f;
}

// ---- layer-2 gather + fused bias/self-loop/log_softmax -> out (stride 7) ----
__global__ __launch_bounds__(256) void agg2_kernel(const int* __restrict__ row_ptr,
                                                   const int* __restrict__ row_end,
                                                   const int* __restrict__ adj,
                                                   const float* __restrict__ h,
                                                   const float* __restrict__ dinv,
                                                   const float* __restrict__ b2,
                                                   float* __restrict__ out, int n) {
    int t = blockIdx.x * 256 + threadIdx.x;
    int node = t >> 3, j = t & 7;
    if (node >= n) return;
    int s = row_ptr[node], e = row_end[node];
    float a0 = 0.0f, a1 = 0.0f;
    int k = s;
    for (; k + 1 < e; k += 2) {
        int s0 = adj[k], s1 = adj[k + 1];
        a0 += h[(size_t)s0 * 8 + j];
        a1 += h[(size_t)s1 * 8 + j];
    }
    if (k < e) a0 += h[(size_t)adj[k] * 8 + j];
    float di = dinv[node];
    float bj = j < F2 ? b2[j] : 0.0f;
    float v = di * (a0 + a1 + h[(size_t)node * 8 + j]) + bj;
    if (j >= F2) v = -INFINITY;
    float m = v;
#pragma unroll
    for (int w = 1; w < 8; w <<= 1) m = fmaxf(m, __shfl_xor(m, w, 8));
    float ex = (j < F2) ? expf(v - m) : 0.0f;
    float sum = ex;
#pragma unroll
    for (int w = 1; w < 8; w <<= 1) sum += __shfl_xor(sum, w, 8);
    float lse = m + logf(sum);
    if (j < F2) out[(size_t)node * F2 + j] = v - lse;
}

extern "C" void kernel_launch(void* const* d_in, const int* in_sizes, int n_in,
                              void* d_out, int out_size, void* d_ws, size_t ws_size,
                              hipStream_t stream) {
    const float* x  = (const float*)d_in[0];
    const int*   ei = (const int*)d_in[1];
    const float* W1 = (const float*)d_in[2];
    const float* b1 = (const float*)d_in[3];
    const float* W2 = (const float*)d_in[4];
    const float* b2 = (const float*)d_in[5];

    int n = in_sizes[0] / D_IN;
    int E = in_sizes[1] / 2;
    const int* src = ei;
    const int* dst = ei + E;
    int NB = (n + 255) >> BKT_SHIFT;

    char* ws = (char*)d_ws;
    size_t o = 0;
    int* bucket_cnt    = (int*)(ws + o); o += 512 * 4;
    int* bucket_base   = (int*)(ws + o); o += 516 * 4;
    int* bucket_cursor = (int*)(ws + o); o += 512 * 4;
    int*   row_ptr = (int*)(ws + o);   o += (size_t)n * 4;
    int*   row_end = (int*)(ws + o);   o += (size_t)n * 4;
    float* dinv    = (float*)(ws + o); o += (size_t)n * 4;
    int*   adj     = (int*)(ws + o);   o += (size_t)E * 4;
    size_t uni = (size_t)E > (size_t)n * 32 ? (size_t)E : (size_t)n * 32;
    unsigned int* binned = (unsigned int*)(ws + o);
    float* h1s  = (float*)(ws + o);                    // overwrites binned after csr pass
    float* acc1 = (float*)(ws + o) + (size_t)n * F1;
    o += uni * 4;
    float* h2s = h1s;
    float* out = (float*)d_out;

    const int B = 256;
    int GA = (E + A_CHUNK - 1) / A_CHUNK;
    int gN = (n + B - 1) / B;

    hipMemsetAsync(bucket_cnt, 0, 512 * sizeof(int), stream);

    binhist_kernel<<<GA, B, 0, stream>>>(dst, bucket_cnt, E, NB);
    bucketscan_kernel<<<1, 512, 0, stream>>>(bucket_cnt, bucket_base, bucket_cursor, NB, E);
    bin_kernel<<<GA, B, 0, stream>>>(src, dst, bucket_cursor, binned, E, NB);
    csr_kernel<<<NB, B, 0, stream>>>(binned, bucket_base, row_ptr, row_end, dinv, adj, n);

    // 512 blocks = 2048 waves (8 waves/CU at ~180 VGPR), grid-stride over nodes
    mm1_kernel<<<512, B, 0, stream>>>(x, W1, dinv, h1s, n);

    agg1_kernel<<<((size_t)n * F1 + B - 1) / B, B, 0, stream>>>(row_ptr, row_end, adj, h1s, dinv, b1, acc1, n);

    mm2_kernel<<<gN, B, 0, stream>>>(acc1, W2, dinv, h2s, n);

    agg2_kernel<<<((size_t)n * 8 + B - 1) / B, B, 0, stream>>>(row_ptr, row_end, adj, h2s, dinv, b2, out, n);
}